// Round 8
// baseline (862.233 us; speedup 1.0000x reference)
//
#include <hip/hip_runtime.h>
#include <stdint.h>

// ---------------- problem constants ----------------
#define B_TOK   16384
#define D_IN    2048
#define H_DIM   1024
#define NEXP    64
#define CAPACITY 640   // ceil(16384*2/64 * 1.25)

typedef __attribute__((ext_vector_type(8))) _Float16 half8;
typedef __attribute__((ext_vector_type(4))) float f32x4;

// f32 -> 2x fp16 limbs: a ≈ ah + am'*2^-12, am' = (a-ah)*4096 stored pre-scaled (normal range).
// For |a| < 2^-13 use ah=0 so ah is never subnormal; am' = a*4096.
__device__ __forceinline__ void split16(float a, unsigned short& uh, unsigned short& ul) {
  union { _Float16 h; unsigned short u; } c;
  _Float16 h1 = (fabsf(a) < 1.220703125e-4f) ? (_Float16)0.0f : (_Float16)a;
  c.h = h1; uh = c.u;
  float r = (a - (float)h1) * 4096.0f;
  c.h = (_Float16)r; ul = c.u;
}

__device__ __forceinline__ void gload_lds16(const void* g, void* l) {
  __builtin_amdgcn_global_load_lds(
      (const __attribute__((address_space(1))) void*)g,
      (__attribute__((address_space(3))) void*)l, 16, 0, 0);
}

// ---------------- conv A: x[16384][2048] f32 -> A2[16384][4096] f16 = [ah | am'] ----------------
__global__ __launch_bounds__(256) void k_convA(const float* __restrict__ x,
                                               unsigned short* __restrict__ A2) {
  int tid = blockIdx.x * 256 + threadIdx.x;     // 8388608 threads, 4 floats each
  int f0 = tid * 4;
  int t = f0 >> 11;
  int k = f0 & 2047;
  float4 v = *reinterpret_cast<const float4*>(x + f0);
  ushort4 hi, lo;
  split16(v.x, hi.x, lo.x);
  split16(v.y, hi.y, lo.y);
  split16(v.z, hi.z, lo.z);
  split16(v.w, hi.w, lo.w);
  unsigned short* row = A2 + (size_t)t * 4096;
  *reinterpret_cast<ushort4*>(row + k)        = hi;
  *reinterpret_cast<ushort4*>(row + 2048 + k) = lo;
}

// ---------------- conv B: W1[2048][1024] f32 -> B2t[1024][4096] f16 = [wh | wm'] (transposed) ----------------
__global__ __launch_bounds__(256) void k_convB(const float* __restrict__ W1,
                                               unsigned short* __restrict__ B2t) {
  __shared__ float tile[32][33];
  int k0 = blockIdx.x * 32;   // 64 tiles over K=2048
  int n0 = blockIdx.y * 32;   // 32 tiles over N=1024
  int tx = threadIdx.x;       // 0..31
  int ty = threadIdx.y;       // 0..7
  #pragma unroll
  for (int i = 0; i < 32; i += 8)
    tile[ty + i][tx] = W1[(size_t)(k0 + ty + i) * 1024 + n0 + tx];
  __syncthreads();
  #pragma unroll
  for (int i = 0; i < 32; i += 8) {
    int n = n0 + ty + i;
    int k = k0 + tx;
    unsigned short uh, ul;
    split16(tile[tx][ty + i], uh, ul);
    unsigned short* row = B2t + (size_t)n * 4096;
    row[k]        = uh;
    row[2048 + k] = ul;
  }
}

// ---------------- GEMM1: h = silu(x@W1 + b1) via fp16 2-limb split, M=16384 N=1024 ------------
// Phase A (32 tiles): acc_c  = S(am'*wm')          ; acc_c *= 2^-12
// Phase B (32 fat tiles, 4 halves staged, 96 MFMA/tile):
//         acc_c += S(ah*wm') + S(am'*wh)   and   acc_h = S(ah*wh)
// Final:  out = acc_c*2^-12 + acc_h  = S_mm*2^-24 + (S_hm'+S_m'h)*2^-12 + S_hh
// (same error structure as the verified 4-region version; staging/barriers halved)
//
// LDS swizzle (T2, both-sides, verified r6->r7): linear gload_lds dest + pre-swizzled
// global source column-block (lane l: (l&7)^((l>>3)&7)) + XOR'd read offset.
__global__ __launch_bounds__(256) void k_gemm1(const unsigned short* __restrict__ A2,
                                               const unsigned short* __restrict__ B2t,
                                               const float* __restrict__ b1,
                                               float* __restrict__ h) {
  __shared__ unsigned short Ah[128 * 64];
  __shared__ unsigned short Am[128 * 64];
  __shared__ unsigned short Bh[128 * 64];
  __shared__ unsigned short Bm[128 * 64];
  int bid = blockIdx.x;                         // 1024 = 128 * 8
  int wg  = ((bid & 7) << 7) | (bid >> 3);      // XCD-bijective swizzle (1024 % 8 == 0)
  int bm_ = wg >> 3;
  int bn_ = wg & 7;
  int row0 = bm_ << 7;
  int col0 = bn_ << 7;
  int tid  = threadIdx.x;
  int w    = tid >> 6;
  int lane = tid & 63;
  int wr = (w >> 1) << 6;                       // wave output 64x64
  int wc = (w & 1) << 6;

  int rsub = lane >> 3;                         // 0..7 rows within 1KB issue
  int csub = (((lane & 7) ^ ((lane >> 3) & 7)) << 3);  // pre-swizzled source col (elems)

  f32x4 acc_c[4][4] = {};
  f32x4 acc_h[4][4] = {};

  int arow = wr + (lane & 15);
  int brow = wc + (lane & 15);
  int r7   = lane & 7;
  int cbase = lane >> 4;                        // col-block base 0..3

  // ---- Phase A: am' * wm' ----
  for (int kt = 0; kt < 32; ++kt) {
    int kk0 = kt * 64;
    #pragma unroll
    for (int j = 0; j < 4; ++j) {
      int rs = (w * 4 + j) * 8;
      const unsigned short* ga = A2 + (size_t)(row0 + rs + rsub) * 4096 + 2048 + kk0 + csub;
      gload_lds16(ga, (char*)Am + (w * 4 + j) * 1024);
      const unsigned short* gb = B2t + (size_t)(col0 + rs + rsub) * 4096 + 2048 + kk0 + csub;
      gload_lds16(gb, (char*)Bm + (w * 4 + j) * 1024);
    }
    __syncthreads();
    #pragma unroll
    for (int kk = 0; kk < 2; ++kk) {
      int cofs = ((kk * 4 + cbase) ^ r7) << 3;
      half8 am_f[4], bm_f[4];
      #pragma unroll
      for (int m = 0; m < 4; ++m)
        am_f[m] = *reinterpret_cast<const half8*>(Am + (arow + m * 16) * 64 + cofs);
      #pragma unroll
      for (int n = 0; n < 4; ++n)
        bm_f[n] = *reinterpret_cast<const half8*>(Bm + (brow + n * 16) * 64 + cofs);
      #pragma unroll
      for (int m = 0; m < 4; ++m)
        #pragma unroll
        for (int n = 0; n < 4; ++n)
          acc_c[m][n] = __builtin_amdgcn_mfma_f32_16x16x32_f16(am_f[m], bm_f[n], acc_c[m][n], 0, 0, 0);
    }
    __syncthreads();
  }

  #pragma unroll
  for (int m = 0; m < 4; ++m)
    #pragma unroll
    for (int n = 0; n < 4; ++n)
      acc_c[m][n] *= 2.44140625e-4f;   // * 2^-12

  // ---- Phase B: fused {ah*wm', am'*wh} -> acc_c and {ah*wh} -> acc_h ----
  for (int kt = 0; kt < 32; ++kt) {
    int kk0 = kt * 64;
    #pragma unroll
    for (int j = 0; j < 4; ++j) {
      int rs = (w * 4 + j) * 8;
      size_t garow = (size_t)(row0 + rs + rsub) * 4096 + kk0 + csub;
      size_t gbrow = (size_t)(col0 + rs + rsub) * 4096 + kk0 + csub;
      gload_lds16(A2 + garow,        (char*)Ah + (w * 4 + j) * 1024);
      gload_lds16(A2 + garow + 2048, (char*)Am + (w * 4 + j) * 1024);
      gload_lds16(B2t + gbrow,        (char*)Bh + (w * 4 + j) * 1024);
      gload_lds16(B2t + gbrow + 2048, (char*)Bm + (w * 4 + j) * 1024);
    }
    __syncthreads();
    #pragma unroll
    for (int kk = 0; kk < 2; ++kk) {
      int cofs = ((kk * 4 + cbase) ^ r7) << 3;
      half8 ah_f[4], am_f[4], bh_f[4], bm_f[4];
      #pragma unroll
      for (int m = 0; m < 4; ++m) {
        ah_f[m] = *reinterpret_cast<const half8*>(Ah + (arow + m * 16) * 64 + cofs);
        am_f[m] = *reinterpret_cast<const half8*>(Am + (arow + m * 16) * 64 + cofs);
      }
      #pragma unroll
      for (int n = 0; n < 4; ++n) {
        bh_f[n] = *reinterpret_cast<const half8*>(Bh + (brow + n * 16) * 64 + cofs);
        bm_f[n] = *reinterpret_cast<const half8*>(Bm + (brow + n * 16) * 64 + cofs);
      }
      #pragma unroll
      for (int m = 0; m < 4; ++m)
        #pragma unroll
        for (int n = 0; n < 4; ++n) {
          acc_h[m][n] = __builtin_amdgcn_mfma_f32_16x16x32_f16(ah_f[m], bh_f[n], acc_h[m][n], 0, 0, 0);
          acc_c[m][n] = __builtin_amdgcn_mfma_f32_16x16x32_f16(ah_f[m], bm_f[n], acc_c[m][n], 0, 0, 0);
          acc_c[m][n] = __builtin_amdgcn_mfma_f32_16x16x32_f16(am_f[m], bh_f[n], acc_c[m][n], 0, 0, 0);
        }
    }
    __syncthreads();
  }

  // epilogue: fold limbs, bias + silu, store f32 h. C/D map: col=lane&15, row=(lane>>4)*4+j
  int crow0 = row0 + wr + ((lane >> 4) << 2);
  int ccol0 = col0 + wc + (lane & 15);
  #pragma unroll
  for (int n = 0; n < 4; ++n) {
    int col = ccol0 + n * 16;
    float bias = b1[col];
    #pragma unroll
    for (int m = 0; m < 4; ++m) {
      #pragma unroll
      for (int j = 0; j < 4; ++j) {
        int row = crow0 + m * 16 + j;
        float v = acc_c[m][n][j] * 2.44140625e-4f + acc_h[m][n][j] + bias;
        float s = v / (1.0f + expf(-v));
        h[(size_t)row * 1024 + col] = s;
      }
    }
  }
}

// ---------------- GEMM2 (fp64 accumulate): logits = h @ W2 + b2, K=1024, N=64 ----------------
__global__ __launch_bounds__(256) void k_gemm2(const float* __restrict__ h,
                                               const float* __restrict__ W2,
                                               const float* __restrict__ b2,
                                               float* __restrict__ logits) {
  __shared__ float ht[32][76];   // [k][token], padded
  __shared__ float wt[32][64];   // [k][expert]
  int t0 = blockIdx.x * 64;      // 256 blocks
  int tid = threadIdx.x;
  int ig = tid & 15;             // token group: tokens ig*4..+3
  int jg = tid >> 4;             // expert group: experts jg*4..+3
  double acc[4][4] = {};

  for (int kc = 0; kc < 32; ++kc) {
    __syncthreads();
    #pragma unroll
    for (int q = 0; q < 8; ++q) {           // 64 tok x 32 k
      int f = tid + q * 256;
      int k = f & 31, t = f >> 5;
      ht[k][t] = h[(size_t)(t0 + t) * 1024 + kc * 32 + k];
    }
    #pragma unroll
    for (int q = 0; q < 8; ++q) {           // 32 k x 64 e
      int f = tid + q * 256;
      int k = f >> 6, e = f & 63;
      wt[k][e] = W2[(size_t)(kc * 32 + k) * 64 + e];
    }
    __syncthreads();
    #pragma unroll
    for (int k = 0; k < 32; ++k) {
      float4 hv = *reinterpret_cast<const float4*>(&ht[k][ig * 4]);
      float4 wv = *reinterpret_cast<const float4*>(&wt[k][jg * 4]);
      double ha[4] = {(double)hv.x, (double)hv.y, (double)hv.z, (double)hv.w};
      double wa[4] = {(double)wv.x, (double)wv.y, (double)wv.z, (double)wv.w};
      #pragma unroll
      for (int a = 0; a < 4; ++a)
        #pragma unroll
        for (int b = 0; b < 4; ++b)
          acc[a][b] += ha[a] * wa[b];
    }
  }
  #pragma unroll
  for (int a = 0; a < 4; ++a) {
    int t = t0 + ig * 4 + a;
    float4 o;
    o.x = (float)(acc[a][0] + (double)b2[jg * 4 + 0]);
    o.y = (float)(acc[a][1] + (double)b2[jg * 4 + 1]);
    o.z = (float)(acc[a][2] + (double)b2[jg * 4 + 2]);
    o.w = (float)(acc[a][3] + (double)b2[jg * 4 + 3]);
    *reinterpret_cast<float4*>(&logits[(size_t)t * 64 + jg * 4]) = o;
  }
}

// ---------------- router: top-2, weights, probs accumulation, top1 counts ----------------
__global__ __launch_bounds__(256) void k_router(const float* __restrict__ logits,
                                                float* __restrict__ out_w,
                                                float* __restrict__ out_idx,
                                                int* __restrict__ idx_ws,
                                                float* __restrict__ cnt,
                                                float* __restrict__ probsum) {
  int tid = threadIdx.x;
  int lane = tid & 63;
  int wv = tid >> 6;
  int gw = blockIdx.x * 4 + wv;        // 1024 waves, 16 tokens each
  float accp = 0.f, accc = 0.f;
  for (int it = 0; it < 16; ++it) {
    int t = gw * 16 + it;
    float v = logits[(size_t)t * 64 + lane];
    // top1 (max, smallest index on tie)
    float bv = v; int bi = lane;
    #pragma unroll
    for (int off = 32; off; off >>= 1) {
      float v2 = __shfl_xor(bv, off);
      int i2 = __shfl_xor(bi, off);
      if (v2 > bv || (v2 == bv && i2 < bi)) { bv = v2; bi = i2; }
    }
    // top2
    float ve = (lane == bi) ? -3.4e38f : v;
    float bv2 = ve; int bi2 = lane;
    #pragma unroll
    for (int off = 32; off; off >>= 1) {
      float v2 = __shfl_xor(bv2, off);
      int i2 = __shfl_xor(bi2, off);
      if (v2 > bv2 || (v2 == bv2 && i2 < bi2)) { bv2 = v2; bi2 = i2; }
    }
    // full softmax (for aux loss)
    float p = expf(v - bv);
    float s = p;
    #pragma unroll
    for (int off = 32; off; off >>= 1) s += __shfl_xor(s, off);
    accp += p / s;
    accc += (lane == bi) ? 1.f : 0.f;
    if (lane == 0) {
      float e21 = expf(bv2 - bv);
      float w0 = 1.f / (1.f + e21);
      out_w[t * 2]     = w0;
      out_w[t * 2 + 1] = e21 / (1.f + e21);
      out_idx[t * 2]     = (float)bi;
      out_idx[t * 2 + 1] = (float)bi2;
      idx_ws[t * 2]     = bi;
      idx_ws[t * 2 + 1] = bi2;
    }
  }
  atomicAdd(&probsum[lane], accp);
  atomicAdd(&cnt[lane], accc);
}

// ---------------- capacity mask: serial k-major scan per expert ----------------
__global__ void k_mask(const int* __restrict__ idx_ws, float* __restrict__ out_mask) {
  const int e = blockIdx.x;        // 64 experts
  const int lane = threadIdx.x;    // 64 lanes
  const unsigned long long lt = (1ull << lane) - 1ull;
  int c = 0;
  for (int k = 0; k < 2; ++k) {
    for (int base = 0; base < B_TOK; base += 256) {
      int i0 = idx_ws[(base +       lane) * 2 + k];
      int i1 = idx_ws[(base + 64  + lane) * 2 + k];
      int i2 = idx_ws[(base + 128 + lane) * 2 + k];
      int i3 = idx_ws[(base + 192 + lane) * 2 + k];
      unsigned long long m0 = __ballot(i0 == e);
      unsigned long long m1 = __ballot(i1 == e);
      unsigned long long m2 = __ballot(i2 == e);
      unsigned long long m3 = __ballot(i3 == e);
      if (i0 == e) out_mask[(base +       lane) * 2 + k] = (c + __popcll(m0 & lt) >= CAPACITY) ? 1.f : 0.f;
      c += __popcll(m0);
      if (i1 == e) out_mask[(base + 64  + lane) * 2 + k] = (c + __popcll(m1 & lt) >= CAPACITY) ? 1.f : 0.f;
      c += __popcll(m1);
      if (i2 == e) out_mask[(base + 128 + lane) * 2 + k] = (c + __popcll(m2 & lt) >= CAPACITY) ? 1.f : 0.f;
      c += __popcll(m2);
      if (i3 == e) out_mask[(base + 192 + lane) * 2 + k] = (c + __popcll(m3 & lt) >= CAPACITY) ? 1.f : 0.f;
      c += __popcll(m3);
    }
  }
}

// ---------------- aux loss ----------------
__global__ void k_aux(const float* __restrict__ cnt, const float* __restrict__ probsum,
                      float* __restrict__ out_aux) {
  int lane = threadIdx.x;  // 64
  float v = (cnt[lane] * (1.f / 16384.f)) * (probsum[lane] * (1.f / 16384.f));
  #pragma unroll
  for (int off = 32; off; off >>= 1) v += __shfl_xor(v, off);
  if (lane == 0) out_aux[0] = v * 64.f;
}

// ---------------- launch ----------------
extern "C" void kernel_launch(void* const* d_in, const int* in_sizes, int n_in,
                              void* d_out, int out_size, void* d_ws, size_t ws_size,
                              hipStream_t stream) {
  const float* x  = (const float*)d_in[0];
  const float* W1 = (const float*)d_in[1];
  const float* b1 = (const float*)d_in[2];
  const float* W2 = (const float*)d_in[3];
  const float* b2 = (const float*)d_in[4];

  char* ws = (char*)d_ws;
  // ws layout: A2 134217728 | B2t 8388608 | h 67108864  (total 209715200 B = 200 MiB)
  unsigned short* A2  = (unsigned short*)ws;
  unsigned short* B2t = (unsigned short*)(ws + 134217728);
  float* h            = (float*)(ws + 142606336);
  // after gemm1/gemm2, the A2 region is dead: reuse for logits / idx / accumulators
  float* logits = (float*)ws;
  int*   idx_ws = (int*)(ws + 4194304);
  float* cnt     = (float*)(ws + 4325376);
  float* probsum = (float*)(ws + 4325376 + 256);

  float* out      = (float*)d_out;
  float* out_w    = out;           // [16384,2]
  float* out_idx  = out + 32768;   // [16384,2] written as float
  float* out_aux  = out + 65536;   // scalar
  float* out_mask = out + 65537;   // [16384,2] written as 0.0/1.0

  hipLaunchKernelGGL(k_convA, dim3(32768), dim3(256), 0, stream, x, A2);
  hipLaunchKernelGGL(k_convB, dim3(64, 32), dim3(32, 8), 0, stream, W1, B2t);
  hipLaunchKernelGGL(k_gemm1, dim3(1024), dim3(256), 0, stream, A2, B2t, b1, h);
  hipLaunchKernelGGL(k_gemm2, dim3(256), dim3(256), 0, stream, h, W2, b2, logits);
  hipMemsetAsync(ws + 4325376, 0, 512, stream);
  hipLaunchKernelGGL(k_router, dim3(256), dim3(256), 0, stream,
                     logits, out_w, out_idx, idx_ws, cnt, probsum);
  hipLaunchKernelGGL(k_mask, dim3(64), dim3(64), 0, stream, idx_ws, out_mask);
  hipLaunchKernelGGL(k_aux, dim3(1), dim3(64), 0, stream, cnt, probsum, out_aux);
}

// Round 9
// 672.844 us; speedup vs baseline: 1.2815x; 1.2815x over previous
//
#include <hip/hip_runtime.h>
#include <stdint.h>

// ---------------- problem constants ----------------
#define B_TOK   16384
#define D_IN    2048
#define H_DIM   1024
#define NEXP    64
#define CAPACITY 640   // ceil(16384*2/64 * 1.25)

typedef __attribute__((ext_vector_type(8))) _Float16 half8;
typedef __attribute__((ext_vector_type(4))) float f32x4;

// f32 -> 2x fp16 limbs: a ≈ ah + am'*2^-12, am' = (a-ah)*4096 stored pre-scaled (normal range).
// For |a| < 2^-13 use ah=0 so ah is never subnormal; am' = a*4096.
__device__ __forceinline__ void split16(float a, unsigned short& uh, unsigned short& ul) {
  union { _Float16 h; unsigned short u; } c;
  _Float16 h1 = (fabsf(a) < 1.220703125e-4f) ? (_Float16)0.0f : (_Float16)a;
  c.h = h1; uh = c.u;
  float r = (a - (float)h1) * 4096.0f;
  c.h = (_Float16)r; ul = c.u;
}

__device__ __forceinline__ void gload_lds16(const void* g, void* l) {
  __builtin_amdgcn_global_load_lds(
      (const __attribute__((address_space(1))) void*)g,
      (__attribute__((address_space(3))) void*)l, 16, 0, 0);
}

// ---------------- conv A: x[16384][2048] f32 -> A2[16384][4096] f16 = [ah | am'] ----------------
__global__ __launch_bounds__(256) void k_convA(const float* __restrict__ x,
                                               unsigned short* __restrict__ A2) {
  int tid = blockIdx.x * 256 + threadIdx.x;     // 8388608 threads, 4 floats each
  int f0 = tid * 4;
  int t = f0 >> 11;
  int k = f0 & 2047;
  float4 v = *reinterpret_cast<const float4*>(x + f0);
  ushort4 hi, lo;
  split16(v.x, hi.x, lo.x);
  split16(v.y, hi.y, lo.y);
  split16(v.z, hi.z, lo.z);
  split16(v.w, hi.w, lo.w);
  unsigned short* row = A2 + (size_t)t * 4096;
  *reinterpret_cast<ushort4*>(row + k)        = hi;
  *reinterpret_cast<ushort4*>(row + 2048 + k) = lo;
}

// ---------------- conv B: W1[2048][1024] f32 -> B2t[1024][4096] f16 = [wh | wm'] (transposed) ----------------
__global__ __launch_bounds__(256) void k_convB(const float* __restrict__ W1,
                                               unsigned short* __restrict__ B2t) {
  __shared__ float tile[32][33];
  int k0 = blockIdx.x * 32;   // 64 tiles over K=2048
  int n0 = blockIdx.y * 32;   // 32 tiles over N=1024
  int tx = threadIdx.x;       // 0..31
  int ty = threadIdx.y;       // 0..7
  #pragma unroll
  for (int i = 0; i < 32; i += 8)
    tile[ty + i][tx] = W1[(size_t)(k0 + ty + i) * 1024 + n0 + tx];
  __syncthreads();
  #pragma unroll
  for (int i = 0; i < 32; i += 8) {
    int n = n0 + ty + i;
    int k = k0 + tx;
    unsigned short uh, ul;
    split16(tile[tx][ty + i], uh, ul);
    unsigned short* row = B2t + (size_t)n * 4096;
    row[k]        = uh;
    row[2048 + k] = ul;
  }
}

// ---------------- GEMM1: h = silu(x@W1 + b1) via fp16 2-limb split, M=16384 N=1024 ------------
// (round-7 verified state: 330us, MfmaUtil 38%, bank conflicts 0)
// 4 regions, each K=2048 (32 kt of BK=64), single accumulator with staged rescale:
//   acc  = S(am'*wm')                 ; acc *= 2^-12
//   acc += S(ah*wm') + S(am'*wh)      ; acc *= 2^-12
//   acc += S(ah*wh)                   (main term last)
// LDS swizzle (T2, both-sides): linear gload_lds dest + pre-swizzled global source
// column-block (lane l: (l&7)^((l>>3)&7)) + XOR'd read offset.
__global__ __launch_bounds__(256) void k_gemm1(const unsigned short* __restrict__ A2,
                                               const unsigned short* __restrict__ B2t,
                                               const float* __restrict__ b1,
                                               float* __restrict__ h) {
  __shared__ unsigned short Al[128 * 64];
  __shared__ unsigned short Bl[128 * 64];
  int bid = blockIdx.x;                         // 1024 = 128 * 8
  int wg  = ((bid & 7) << 7) | (bid >> 3);      // XCD-bijective swizzle (1024 % 8 == 0)
  int bm  = wg >> 3;
  int bn  = wg & 7;
  int row0 = bm << 7;
  int col0 = bn << 7;
  int tid  = threadIdx.x;
  int w    = tid >> 6;
  int lane = tid & 63;
  int wr = (w >> 1) << 6;                       // wave output 64x64
  int wc = (w & 1) << 6;

  int rsub = lane >> 3;                         // 0..7 rows within 1KB issue
  int csub = (((lane & 7) ^ ((lane >> 3) & 7)) << 3);  // pre-swizzled source col (elems)

  f32x4 acc[4][4] = {};

  int arow = wr + (lane & 15);
  int brow = wc + (lane & 15);
  int r7   = lane & 7;                          // row&7 for all fragment rows
  int cbase = lane >> 4;                        // col-block base 0..3

  auto do_region = [&](int aoff, int boff) {
    for (int kt = 0; kt < 32; ++kt) {
      int kk0 = kt * 64;
      #pragma unroll
      for (int j = 0; j < 4; ++j) {
        int rs = (w * 4 + j) * 8;
        const unsigned short* ga = A2 + (size_t)(row0 + rs + rsub) * 4096 + aoff + kk0 + csub;
        gload_lds16(ga, (char*)Al + (w * 4 + j) * 1024);
        const unsigned short* gb = B2t + (size_t)(col0 + rs + rsub) * 4096 + boff + kk0 + csub;
        gload_lds16(gb, (char*)Bl + (w * 4 + j) * 1024);
      }
      __syncthreads();
      #pragma unroll
      for (int kk = 0; kk < 2; ++kk) {
        int cofs = ((kk * 4 + cbase) ^ r7) << 3;   // swizzled read col offset (elems)
        half8 af[4], bfr[4];
        #pragma unroll
        for (int m = 0; m < 4; ++m)
          af[m] = *reinterpret_cast<const half8*>(Al + (arow + m * 16) * 64 + cofs);
        #pragma unroll
        for (int n = 0; n < 4; ++n)
          bfr[n] = *reinterpret_cast<const half8*>(Bl + (brow + n * 16) * 64 + cofs);
        #pragma unroll
        for (int m = 0; m < 4; ++m)
          #pragma unroll
          for (int n = 0; n < 4; ++n)
            acc[m][n] = __builtin_amdgcn_mfma_f32_16x16x32_f16(af[m], bfr[n], acc[m][n], 0, 0, 0);
      }
      __syncthreads();
    }
  };

  auto scale_acc = [&](float s) {
    #pragma unroll
    for (int m = 0; m < 4; ++m)
      #pragma unroll
      for (int n = 0; n < 4; ++n)
        acc[m][n] *= s;
  };

  do_region(2048, 2048);               // am' * wm'
  scale_acc(2.44140625e-4f);           // * 2^-12
  do_region(0, 2048);                  // ah  * wm'
  do_region(2048, 0);                  // am' * wh
  scale_acc(2.44140625e-4f);           // * 2^-12
  do_region(0, 0);                     // ah  * wh  (main term)

  // epilogue: bias + silu, store f32 h. C/D map: col=lane&15, row=(lane>>4)*4+j
  int crow0 = row0 + wr + ((lane >> 4) << 2);
  int ccol0 = col0 + wc + (lane & 15);
  #pragma unroll
  for (int n = 0; n < 4; ++n) {
    int col = ccol0 + n * 16;
    float bias = b1[col];
    #pragma unroll
    for (int m = 0; m < 4; ++m) {
      #pragma unroll
      for (int j = 0; j < 4; ++j) {
        int row = crow0 + m * 16 + j;
        float v = acc[m][n][j] + bias;
        float s = v / (1.0f + expf(-v));
        h[(size_t)row * 1024 + col] = s;
      }
    }
  }
}

// ---------------- GEMM2 split-K (fp64 partials, deterministic): K=1024 -> 4 x 256 ----------------
// grid (256, 4): block (t0 = bx*64 tokens, kseg = by). Partial f64 sums, no bias.
__global__ __launch_bounds__(256) void k_gemm2p(const float* __restrict__ h,
                                                const float* __restrict__ W2,
                                                double* __restrict__ part) {
  __shared__ float ht[32][76];   // [k][token], padded
  __shared__ float wt[32][64];   // [k][expert]
  int t0 = blockIdx.x * 64;
  int kbase = blockIdx.y * 256;  // K segment
  int tid = threadIdx.x;
  int ig = tid & 15;             // token group: tokens ig*4..+3
  int jg = tid >> 4;             // expert group: experts jg*4..+3
  double acc[4][4] = {};

  for (int kc = 0; kc < 8; ++kc) {
    __syncthreads();
    #pragma unroll
    for (int q = 0; q < 8; ++q) {           // 64 tok x 32 k
      int f = tid + q * 256;
      int k = f & 31, t = f >> 5;
      ht[k][t] = h[(size_t)(t0 + t) * 1024 + kbase + kc * 32 + k];
    }
    #pragma unroll
    for (int q = 0; q < 8; ++q) {           // 32 k x 64 e
      int f = tid + q * 256;
      int k = f >> 6, e = f & 63;
      wt[k][e] = W2[(size_t)(kbase + kc * 32 + k) * 64 + e];
    }
    __syncthreads();
    #pragma unroll
    for (int k = 0; k < 32; ++k) {
      float4 hv = *reinterpret_cast<const float4*>(&ht[k][ig * 4]);
      float4 wv = *reinterpret_cast<const float4*>(&wt[k][jg * 4]);
      double ha[4] = {(double)hv.x, (double)hv.y, (double)hv.z, (double)hv.w};
      double wa[4] = {(double)wv.x, (double)wv.y, (double)wv.z, (double)wv.w};
      #pragma unroll
      for (int a = 0; a < 4; ++a)
        #pragma unroll
        for (int b = 0; b < 4; ++b)
          acc[a][b] += ha[a] * wa[b];
    }
  }
  double* seg = part + (size_t)blockIdx.y * (B_TOK * NEXP);
  #pragma unroll
  for (int a = 0; a < 4; ++a) {
    int t = t0 + ig * 4 + a;
    #pragma unroll
    for (int b = 0; b < 4; ++b)
      seg[(size_t)t * 64 + jg * 4 + b] = acc[a][b];
  }
}

// ---------------- router: fold f64 partials + b2, top-2, weights, aux accumulation ----------------
__global__ __launch_bounds__(256) void k_router(const double* __restrict__ part,
                                                const float* __restrict__ b2,
                                                float* __restrict__ out_w,
                                                float* __restrict__ out_idx,
                                                int* __restrict__ idx_ws,
                                                float* __restrict__ cnt,
                                                float* __restrict__ probsum) {
  int tid = threadIdx.x;
  int lane = tid & 63;
  int wv = tid >> 6;
  int gw = blockIdx.x * 4 + wv;        // 1024 waves, 16 tokens each
  const size_t seg = (size_t)B_TOK * NEXP;
  float accp = 0.f, accc = 0.f;
  for (int it = 0; it < 16; ++it) {
    int t = gw * 16 + it;
    size_t o = (size_t)t * 64 + lane;
    double sum = part[o] + part[o + seg] + part[o + 2 * seg] + part[o + 3 * seg]
               + (double)b2[lane];
    float v = (float)sum;
    // top1 (max, smallest index on tie)
    float bv = v; int bi = lane;
    #pragma unroll
    for (int off = 32; off; off >>= 1) {
      float v2 = __shfl_xor(bv, off);
      int i2 = __shfl_xor(bi, off);
      if (v2 > bv || (v2 == bv && i2 < bi)) { bv = v2; bi = i2; }
    }
    // top2
    float ve = (lane == bi) ? -3.4e38f : v;
    float bv2 = ve; int bi2 = lane;
    #pragma unroll
    for (int off = 32; off; off >>= 1) {
      float v2 = __shfl_xor(bv2, off);
      int i2 = __shfl_xor(bi2, off);
      if (v2 > bv2 || (v2 == bv2 && i2 < bi2)) { bv2 = v2; bi2 = i2; }
    }
    // full softmax (for aux loss)
    float p = expf(v - bv);
    float s = p;
    #pragma unroll
    for (int off = 32; off; off >>= 1) s += __shfl_xor(s, off);
    accp += p / s;
    accc += (lane == bi) ? 1.f : 0.f;
    if (lane == 0) {
      float e21 = expf(bv2 - bv);
      float w0 = 1.f / (1.f + e21);
      out_w[t * 2]     = w0;
      out_w[t * 2 + 1] = e21 / (1.f + e21);
      out_idx[t * 2]     = (float)bi;
      out_idx[t * 2 + 1] = (float)bi2;
      idx_ws[t * 2]     = bi;
      idx_ws[t * 2 + 1] = bi2;
    }
  }
  atomicAdd(&probsum[lane], accp);
  atomicAdd(&cnt[lane], accc);
}

// ---------------- capacity mask: serial k-major scan per expert ----------------
__global__ void k_mask(const int* __restrict__ idx_ws, float* __restrict__ out_mask) {
  const int e = blockIdx.x;        // 64 experts
  const int lane = threadIdx.x;    // 64 lanes
  const unsigned long long lt = (1ull << lane) - 1ull;
  int c = 0;
  for (int k = 0; k < 2; ++k) {
    for (int base = 0; base < B_TOK; base += 256) {
      int i0 = idx_ws[(base +       lane) * 2 + k];
      int i1 = idx_ws[(base + 64  + lane) * 2 + k];
      int i2 = idx_ws[(base + 128 + lane) * 2 + k];
      int i3 = idx_ws[(base + 192 + lane) * 2 + k];
      unsigned long long m0 = __ballot(i0 == e);
      unsigned long long m1 = __ballot(i1 == e);
      unsigned long long m2 = __ballot(i2 == e);
      unsigned long long m3 = __ballot(i3 == e);
      if (i0 == e) out_mask[(base +       lane) * 2 + k] = (c + __popcll(m0 & lt) >= CAPACITY) ? 1.f : 0.f;
      c += __popcll(m0);
      if (i1 == e) out_mask[(base + 64  + lane) * 2 + k] = (c + __popcll(m1 & lt) >= CAPACITY) ? 1.f : 0.f;
      c += __popcll(m1);
      if (i2 == e) out_mask[(base + 128 + lane) * 2 + k] = (c + __popcll(m2 & lt) >= CAPACITY) ? 1.f : 0.f;
      c += __popcll(m2);
      if (i3 == e) out_mask[(base + 192 + lane) * 2 + k] = (c + __popcll(m3 & lt) >= CAPACITY) ? 1.f : 0.f;
      c += __popcll(m3);
    }
  }
}

// ---------------- aux loss ----------------
__global__ void k_aux(const float* __restrict__ cnt, const float* __restrict__ probsum,
                      float* __restrict__ out_aux) {
  int lane = threadIdx.x;  // 64
  float v = (cnt[lane] * (1.f / 16384.f)) * (probsum[lane] * (1.f / 16384.f));
  #pragma unroll
  for (int off = 32; off; off >>= 1) v += __shfl_xor(v, off);
  if (lane == 0) out_aux[0] = v * 64.f;
}

// ---------------- launch ----------------
extern "C" void kernel_launch(void* const* d_in, const int* in_sizes, int n_in,
                              void* d_out, int out_size, void* d_ws, size_t ws_size,
                              hipStream_t stream) {
  const float* x  = (const float*)d_in[0];
  const float* W1 = (const float*)d_in[1];
  const float* b1 = (const float*)d_in[2];
  const float* W2 = (const float*)d_in[3];
  const float* b2 = (const float*)d_in[4];

  char* ws = (char*)d_ws;
  // ws layout: A2 134217728 | B2t 8388608 | h 67108864  (total 209715200 B = 200 MiB)
  unsigned short* A2  = (unsigned short*)ws;
  unsigned short* B2t = (unsigned short*)(ws + 134217728);
  float* h            = (float*)(ws + 142606336);
  // after gemm1, the A2 region is dead: reuse for f64 partials / idx / accumulators
  double* part  = (double*)ws;                       // [4][16384][64] f64 = 32 MiB
  int*   idx_ws = (int*)(ws + 33554432);             // 128 KiB
  float* cnt     = (float*)(ws + 33554432 + 131072);
  float* probsum = (float*)(ws + 33554432 + 131072 + 256);

  float* out      = (float*)d_out;
  float* out_w    = out;           // [16384,2]
  float* out_idx  = out + 32768;   // [16384,2] written as float
  float* out_aux  = out + 65536;   // scalar
  float* out_mask = out + 65537;   // [16384,2] written as 0.0/1.0

  hipLaunchKernelGGL(k_convA, dim3(32768), dim3(256), 0, stream, x, A2);
  hipLaunchKernelGGL(k_convB, dim3(64, 32), dim3(32, 8), 0, stream, W1, B2t);
  hipLaunchKernelGGL(k_gemm1, dim3(1024), dim3(256), 0, stream, A2, B2t, b1, h);
  hipLaunchKernelGGL(k_gemm2p, dim3(256, 4), dim3(256), 0, stream, h, W2, part);
  hipMemsetAsync(ws + 33554432 + 131072, 0, 512, stream);
  hipLaunchKernelGGL(k_router, dim3(256), dim3(256), 0, stream,
                     part, b2, out_w, out_idx, idx_ws, cnt, probsum);
  hipLaunchKernelGGL(k_mask, dim3(64), dim3(64), 0, stream, idx_ws, out_mask);
  hipLaunchKernelGGL(k_aux, dim3(1), dim3(64), 0, stream, cnt, probsum, out_aux);
}

// Round 10
// 664.922 us; speedup vs baseline: 1.2967x; 1.0119x over previous
//
#include <hip/hip_runtime.h>
#include <stdint.h>

// ---------------- problem constants ----------------
#define B_TOK   16384
#define D_IN    2048
#define H_DIM   1024
#define NEXP    64
#define CAPACITY 640   // ceil(16384*2/64 * 1.25)

typedef __attribute__((ext_vector_type(8))) _Float16 half8;
typedef __attribute__((ext_vector_type(4))) float f32x4;

// f32 -> 2x fp16 limbs: a ≈ ah + am'*2^-12, am' = (a-ah)*4096 stored pre-scaled (normal range).
// For |a| < 2^-13 use ah=0 so ah is never subnormal; am' = a*4096.
__device__ __forceinline__ void split16(float a, unsigned short& uh, unsigned short& ul) {
  union { _Float16 h; unsigned short u; } c;
  _Float16 h1 = (fabsf(a) < 1.220703125e-4f) ? (_Float16)0.0f : (_Float16)a;
  c.h = h1; uh = c.u;
  float r = (a - (float)h1) * 4096.0f;
  c.h = (_Float16)r; ul = c.u;
}

__device__ __forceinline__ void gload_lds16(const void* g, void* l) {
  __builtin_amdgcn_global_load_lds(
      (const __attribute__((address_space(1))) void*)g,
      (__attribute__((address_space(3))) void*)l, 16, 0, 0);
}

// ---------------- conv A: x[16384][2048] f32 -> A2[16384][4096] f16 = [ah | am'] ----------------
__global__ __launch_bounds__(256) void k_convA(const float* __restrict__ x,
                                               unsigned short* __restrict__ A2) {
  int tid = blockIdx.x * 256 + threadIdx.x;     // 8388608 threads, 4 floats each
  int f0 = tid * 4;
  int t = f0 >> 11;
  int k = f0 & 2047;
  float4 v = *reinterpret_cast<const float4*>(x + f0);
  ushort4 hi, lo;
  split16(v.x, hi.x, lo.x);
  split16(v.y, hi.y, lo.y);
  split16(v.z, hi.z, lo.z);
  split16(v.w, hi.w, lo.w);
  unsigned short* row = A2 + (size_t)t * 4096;
  *reinterpret_cast<ushort4*>(row + k)        = hi;
  *reinterpret_cast<ushort4*>(row + 2048 + k) = lo;
}

// ---------------- conv B: W1[2048][1024] f32 -> B2t[1024][4096] f16 = [wh | wm'] (transposed) ----------------
__global__ __launch_bounds__(256) void k_convB(const float* __restrict__ W1,
                                               unsigned short* __restrict__ B2t) {
  __shared__ float tile[32][33];
  int k0 = blockIdx.x * 32;   // 64 tiles over K=2048
  int n0 = blockIdx.y * 32;   // 32 tiles over N=1024
  int tx = threadIdx.x;       // 0..31
  int ty = threadIdx.y;       // 0..7
  #pragma unroll
  for (int i = 0; i < 32; i += 8)
    tile[ty + i][tx] = W1[(size_t)(k0 + ty + i) * 1024 + n0 + tx];
  __syncthreads();
  #pragma unroll
  for (int i = 0; i < 32; i += 8) {
    int n = n0 + ty + i;
    int k = k0 + tx;
    unsigned short uh, ul;
    split16(tile[tx][ty + i], uh, ul);
    unsigned short* row = B2t + (size_t)n * 4096;
    row[k]        = uh;
    row[2048 + k] = ul;
  }
}

// ---------------- conv W2: W2[1024][64] f32 -> W2t[64][2048] f16 = [wh | wm'] (transposed) ----------------
__global__ __launch_bounds__(256) void k_convW2(const float* __restrict__ W2,
                                                unsigned short* __restrict__ W2t) {
  __shared__ float tile[32][33];
  int k0 = blockIdx.x * 32;   // 32 tiles over K=1024
  int e0 = blockIdx.y * 32;   // 2 tiles over E=64
  int tx = threadIdx.x;       // 0..31
  int ty = threadIdx.y;       // 0..7
  #pragma unroll
  for (int i = 0; i < 32; i += 8)
    tile[ty + i][tx] = W2[(size_t)(k0 + ty + i) * 64 + e0 + tx];
  __syncthreads();
  #pragma unroll
  for (int i = 0; i < 32; i += 8) {
    int e = e0 + ty + i;
    int k = k0 + tx;
    unsigned short uh, ul;
    split16(tile[tx][ty + i], uh, ul);
    unsigned short* row = W2t + (size_t)e * 2048;
    row[k]        = uh;
    row[1024 + k] = ul;
  }
}

// ---------------- GEMM1: h = silu(x@W1 + b1) via fp16 2-limb split, M=16384 N=1024 ------------
// (round-7 verified structure: MfmaUtil 38%, bank conflicts 0)
// Epilogue now writes h as f16 limbs Hh/Hm (for the limb-MFMA gemm2).
__global__ __launch_bounds__(256) void k_gemm1(const unsigned short* __restrict__ A2,
                                               const unsigned short* __restrict__ B2t,
                                               const float* __restrict__ b1,
                                               unsigned short* __restrict__ Hh,
                                               unsigned short* __restrict__ Hm) {
  __shared__ unsigned short Al[128 * 64];
  __shared__ unsigned short Bl[128 * 64];
  int bid = blockIdx.x;                         // 1024 = 128 * 8
  int wg  = ((bid & 7) << 7) | (bid >> 3);      // XCD-bijective swizzle (1024 % 8 == 0)
  int bm  = wg >> 3;
  int bn  = wg & 7;
  int row0 = bm << 7;
  int col0 = bn << 7;
  int tid  = threadIdx.x;
  int w    = tid >> 6;
  int lane = tid & 63;
  int wr = (w >> 1) << 6;                       // wave output 64x64
  int wc = (w & 1) << 6;

  int rsub = lane >> 3;                         // 0..7 rows within 1KB issue
  int csub = (((lane & 7) ^ ((lane >> 3) & 7)) << 3);  // pre-swizzled source col (elems)

  f32x4 acc[4][4] = {};

  int arow = wr + (lane & 15);
  int brow = wc + (lane & 15);
  int r7   = lane & 7;                          // row&7 for all fragment rows
  int cbase = lane >> 4;                        // col-block base 0..3

  auto do_region = [&](int aoff, int boff) {
    for (int kt = 0; kt < 32; ++kt) {
      int kk0 = kt * 64;
      #pragma unroll
      for (int j = 0; j < 4; ++j) {
        int rs = (w * 4 + j) * 8;
        const unsigned short* ga = A2 + (size_t)(row0 + rs + rsub) * 4096 + aoff + kk0 + csub;
        gload_lds16(ga, (char*)Al + (w * 4 + j) * 1024);
        const unsigned short* gb = B2t + (size_t)(col0 + rs + rsub) * 4096 + boff + kk0 + csub;
        gload_lds16(gb, (char*)Bl + (w * 4 + j) * 1024);
      }
      __syncthreads();
      #pragma unroll
      for (int kk = 0; kk < 2; ++kk) {
        int cofs = ((kk * 4 + cbase) ^ r7) << 3;   // swizzled read col offset (elems)
        half8 af[4], bfr[4];
        #pragma unroll
        for (int m = 0; m < 4; ++m)
          af[m] = *reinterpret_cast<const half8*>(Al + (arow + m * 16) * 64 + cofs);
        #pragma unroll
        for (int n = 0; n < 4; ++n)
          bfr[n] = *reinterpret_cast<const half8*>(Bl + (brow + n * 16) * 64 + cofs);
        #pragma unroll
        for (int m = 0; m < 4; ++m)
          #pragma unroll
          for (int n = 0; n < 4; ++n)
            acc[m][n] = __builtin_amdgcn_mfma_f32_16x16x32_f16(af[m], bfr[n], acc[m][n], 0, 0, 0);
      }
      __syncthreads();
    }
  };

  auto scale_acc = [&](float s) {
    #pragma unroll
    for (int m = 0; m < 4; ++m)
      #pragma unroll
      for (int n = 0; n < 4; ++n)
        acc[m][n] *= s;
  };

  do_region(2048, 2048);               // am' * wm'
  scale_acc(2.44140625e-4f);           // * 2^-12
  do_region(0, 2048);                  // ah  * wm'
  do_region(2048, 0);                  // am' * wh
  scale_acc(2.44140625e-4f);           // * 2^-12
  do_region(0, 0);                     // ah  * wh  (main term)

  // epilogue: bias + silu, split to f16 limbs. C/D map: col=lane&15, row=(lane>>4)*4+j
  int crow0 = row0 + wr + ((lane >> 4) << 2);
  int ccol0 = col0 + wc + (lane & 15);
  #pragma unroll
  for (int n = 0; n < 4; ++n) {
    int col = ccol0 + n * 16;
    float bias = b1[col];
    #pragma unroll
    for (int m = 0; m < 4; ++m) {
      #pragma unroll
      for (int j = 0; j < 4; ++j) {
        int row = crow0 + m * 16 + j;
        float v = acc[m][n][j] + bias;
        float s = v / (1.0f + expf(-v));
        unsigned short uh, ul;
        split16(s, uh, ul);
        Hh[(size_t)row * 1024 + col] = uh;
        Hm[(size_t)row * 1024 + col] = ul;
      }
    }
  }
}

// ---------------- GEMM2 (f16-limb MFMA, split-K x2): part[kseg] = h @ W2 partial ------------
// tile 64 tok x 64 exp, K=512 per kseg. 3 terms: acc_h = hh*wh; acc_c = hh*wm' + hm'*wh.
// part = acc_c*2^-12 + acc_h  (f32). Same T2 swizzle as gemm1.
__global__ __launch_bounds__(256) void k_gemm2m(const unsigned short* __restrict__ Hh,
                                                const unsigned short* __restrict__ Hm,
                                                const unsigned short* __restrict__ W2t,
                                                float* __restrict__ part) {
  __shared__ unsigned short Ah[64 * 64];
  __shared__ unsigned short Am[64 * 64];
  __shared__ unsigned short Bh[64 * 64];
  __shared__ unsigned short Bm[64 * 64];
  int t0 = blockIdx.x * 64;
  int kbase = blockIdx.y * 512;
  int tid = threadIdx.x;
  int w = tid >> 6;
  int lane = tid & 63;
  int rsub = lane >> 3;
  int csub = (((lane & 7) ^ ((lane >> 3) & 7)) << 3);
  int r7 = lane & 7;
  int cbase = lane >> 4;
  int arow = (w << 4) + (lane & 15);

  f32x4 acc_h[4] = {};
  f32x4 acc_c[4] = {};

  for (int kt = 0; kt < 8; ++kt) {
    int kk0 = kbase + kt * 64;
    #pragma unroll
    for (int j = 0; j < 2; ++j) {
      int g = w * 2 + j;                    // row-group 0..7 (8 rows each)
      int grow = g * 8 + rsub;
      const unsigned short* gah = Hh + (size_t)(t0 + grow) * 1024 + kk0 + csub;
      gload_lds16(gah, (char*)Ah + g * 1024);
      const unsigned short* gam = Hm + (size_t)(t0 + grow) * 1024 + kk0 + csub;
      gload_lds16(gam, (char*)Am + g * 1024);
      const unsigned short* gbh = W2t + (size_t)grow * 2048 + kk0 + csub;
      gload_lds16(gbh, (char*)Bh + g * 1024);
      const unsigned short* gbm = W2t + (size_t)grow * 2048 + 1024 + kk0 + csub;
      gload_lds16(gbm, (char*)Bm + g * 1024);
    }
    __syncthreads();
    #pragma unroll
    for (int kk = 0; kk < 2; ++kk) {
      int cofs = ((kk * 4 + cbase) ^ r7) << 3;
      half8 a_h = *reinterpret_cast<const half8*>(Ah + arow * 64 + cofs);
      half8 a_m = *reinterpret_cast<const half8*>(Am + arow * 64 + cofs);
      #pragma unroll
      for (int n = 0; n < 4; ++n) {
        int brow = n * 16 + (lane & 15);
        half8 b_h = *reinterpret_cast<const half8*>(Bh + brow * 64 + cofs);
        half8 b_m = *reinterpret_cast<const half8*>(Bm + brow * 64 + cofs);
        acc_h[n] = __builtin_amdgcn_mfma_f32_16x16x32_f16(a_h, b_h, acc_h[n], 0, 0, 0);
        acc_c[n] = __builtin_amdgcn_mfma_f32_16x16x32_f16(a_h, b_m, acc_c[n], 0, 0, 0);
        acc_c[n] = __builtin_amdgcn_mfma_f32_16x16x32_f16(a_m, b_h, acc_c[n], 0, 0, 0);
      }
    }
    __syncthreads();
  }

  float* seg = part + (size_t)blockIdx.y * (B_TOK * NEXP);
  int trow0 = t0 + (w << 4) + ((lane >> 4) << 2);
  int ecol0 = lane & 15;
  #pragma unroll
  for (int n = 0; n < 4; ++n)
    #pragma unroll
    for (int j = 0; j < 4; ++j)
      seg[(size_t)(trow0 + j) * 64 + n * 16 + ecol0] =
          acc_c[n][j] * 2.44140625e-4f + acc_h[n][j];
}

// ---------------- router: fold f32 partials + b2, top-2, weights, aux accumulation ----------------
__global__ __launch_bounds__(256) void k_router(const float* __restrict__ part,
                                                const float* __restrict__ b2,
                                                float* __restrict__ out_w,
                                                float* __restrict__ out_idx,
                                                int* __restrict__ idx_ws,
                                                float* __restrict__ cnt,
                                                float* __restrict__ probsum) {
  int tid = threadIdx.x;
  int lane = tid & 63;
  int wv = tid >> 6;
  int gw = blockIdx.x * 4 + wv;        // 1024 waves, 16 tokens each
  const size_t seg = (size_t)B_TOK * NEXP;
  float accp = 0.f, accc = 0.f;
  for (int it = 0; it < 16; ++it) {
    int t = gw * 16 + it;
    size_t o = (size_t)t * 64 + lane;
    float v = part[o] + part[o + seg] + b2[lane];
    // top1 (max, smallest index on tie)
    float bv = v; int bi = lane;
    #pragma unroll
    for (int off = 32; off; off >>= 1) {
      float v2 = __shfl_xor(bv, off);
      int i2 = __shfl_xor(bi, off);
      if (v2 > bv || (v2 == bv && i2 < bi)) { bv = v2; bi = i2; }
    }
    // top2
    float ve = (lane == bi) ? -3.4e38f : v;
    float bv2 = ve; int bi2 = lane;
    #pragma unroll
    for (int off = 32; off; off >>= 1) {
      float v2 = __shfl_xor(bv2, off);
      int i2 = __shfl_xor(bi2, off);
      if (v2 > bv2 || (v2 == bv2 && i2 < bi2)) { bv2 = v2; bi2 = i2; }
    }
    // full softmax (for aux loss)
    float p = expf(v - bv);
    float s = p;
    #pragma unroll
    for (int off = 32; off; off >>= 1) s += __shfl_xor(s, off);
    accp += p / s;
    accc += (lane == bi) ? 1.f : 0.f;
    if (lane == 0) {
      float e21 = expf(bv2 - bv);
      float w0 = 1.f / (1.f + e21);
      out_w[t * 2]     = w0;
      out_w[t * 2 + 1] = e21 / (1.f + e21);
      out_idx[t * 2]     = (float)bi;
      out_idx[t * 2 + 1] = (float)bi2;
      idx_ws[t * 2]     = bi;
      idx_ws[t * 2 + 1] = bi2;
    }
  }
  atomicAdd(&probsum[lane], accp);
  atomicAdd(&cnt[lane], accc);
}

// ---------------- capacity mask: serial k-major scan per expert ----------------
__global__ void k_mask(const int* __restrict__ idx_ws, float* __restrict__ out_mask) {
  const int e = blockIdx.x;        // 64 experts
  const int lane = threadIdx.x;    // 64 lanes
  const unsigned long long lt = (1ull << lane) - 1ull;
  int c = 0;
  for (int k = 0; k < 2; ++k) {
    for (int base = 0; base < B_TOK; base += 256) {
      int i0 = idx_ws[(base +       lane) * 2 + k];
      int i1 = idx_ws[(base + 64  + lane) * 2 + k];
      int i2 = idx_ws[(base + 128 + lane) * 2 + k];
      int i3 = idx_ws[(base + 192 + lane) * 2 + k];
      unsigned long long m0 = __ballot(i0 == e);
      unsigned long long m1 = __ballot(i1 == e);
      unsigned long long m2 = __ballot(i2 == e);
      unsigned long long m3 = __ballot(i3 == e);
      if (i0 == e) out_mask[(base +       lane) * 2 + k] = (c + __popcll(m0 & lt) >= CAPACITY) ? 1.f : 0.f;
      c += __popcll(m0);
      if (i1 == e) out_mask[(base + 64  + lane) * 2 + k] = (c + __popcll(m1 & lt) >= CAPACITY) ? 1.f : 0.f;
      c += __popcll(m1);
      if (i2 == e) out_mask[(base + 128 + lane) * 2 + k] = (c + __popcll(m2 & lt) >= CAPACITY) ? 1.f : 0.f;
      c += __popcll(m2);
      if (i3 == e) out_mask[(base + 192 + lane) * 2 + k] = (c + __popcll(m3 & lt) >= CAPACITY) ? 1.f : 0.f;
      c += __popcll(m3);
    }
  }
}

// ---------------- aux loss ----------------
__global__ void k_aux(const float* __restrict__ cnt, const float* __restrict__ probsum,
                      float* __restrict__ out_aux) {
  int lane = threadIdx.x;  // 64
  float v = (cnt[lane] * (1.f / 16384.f)) * (probsum[lane] * (1.f / 16384.f));
  #pragma unroll
  for (int off = 32; off; off >>= 1) v += __shfl_xor(v, off);
  if (lane == 0) out_aux[0] = v * 64.f;
}

// ---------------- launch ----------------
extern "C" void kernel_launch(void* const* d_in, const int* in_sizes, int n_in,
                              void* d_out, int out_size, void* d_ws, size_t ws_size,
                              hipStream_t stream) {
  const float* x  = (const float*)d_in[0];
  const float* W1 = (const float*)d_in[1];
  const float* b1 = (const float*)d_in[2];
  const float* W2 = (const float*)d_in[3];
  const float* b2 = (const float*)d_in[4];

  char* ws = (char*)d_ws;
  // ws layout: A2 134217728 | B2t 8388608 | Hh 33554432 | Hm 33554432 | W2t 262144
  // (total 209977344 B; A2 region reused post-gemm1 for partials/idx/accumulators)
  unsigned short* A2  = (unsigned short*)ws;
  unsigned short* B2t = (unsigned short*)(ws + 134217728);
  unsigned short* Hh  = (unsigned short*)(ws + 142606336);
  unsigned short* Hm  = (unsigned short*)(ws + 176160768);
  unsigned short* W2t = (unsigned short*)(ws + 209715200);
  // dead-A2 reuse after gemm1:
  float* part    = (float*)ws;                      // [2][16384][64] f32 = 8 MiB
  int*   idx_ws  = (int*)(ws + 8388608);            // 128 KiB
  float* cnt     = (float*)(ws + 8388608 + 131072);
  float* probsum = (float*)(ws + 8388608 + 131072 + 256);

  float* out      = (float*)d_out;
  float* out_w    = out;           // [16384,2]
  float* out_idx  = out + 32768;   // [16384,2] written as float
  float* out_aux  = out + 65536;   // scalar
  float* out_mask = out + 65537;   // [16384,2] written as 0.0/1.0

  hipLaunchKernelGGL(k_convA, dim3(32768), dim3(256), 0, stream, x, A2);
  hipLaunchKernelGGL(k_convB, dim3(64, 32), dim3(32, 8), 0, stream, W1, B2t);
  hipLaunchKernelGGL(k_convW2, dim3(32, 2), dim3(32, 8), 0, stream, W2, W2t);
  hipLaunchKernelGGL(k_gemm1, dim3(1024), dim3(256), 0, stream, A2, B2t, b1, Hh, Hm);
  hipLaunchKernelGGL(k_gemm2m, dim3(256, 2), dim3(256), 0, stream, Hh, Hm, W2t, part);
  hipMemsetAsync(ws + 8388608 + 131072, 0, 512, stream);
  hipLaunchKernelGGL(k_router, dim3(256), dim3(256), 0, stream,
                     part, b2, out_w, out_idx, idx_ws, cnt, probsum);
  hipLaunchKernelGGL(k_mask, dim3(64), dim3(64), 0, stream, idx_ws, out_mask);
  hipLaunchKernelGGL(k_aux, dim3(1), dim3(64), 0, stream, cnt, probsum, out_aux);
}